// Round 13
// baseline (163.113 us; speedup 1.0000x reference)
//
#include <hip/hip_runtime.h>
#include <cstddef>

// Critic_43104291783486 — round 13: un-starve the W stage.
//  - launch_bounds(256,3): 170-VGPR budget (r12's (256,4) left 0 headroom ->
//    VGPR=64 -> staging chunk-serialized; occupancy was NOT the binder).
//  - W1 stage split: issue 8 coalesced float4 loads (1KB/instr) right after
//    the publish barrier; commit (cvt + b128 writes) after compute+reads
//    barrier -> latency hides under 16 MFMA + ds_reads (T14).
//  - W1 LDS col-swizzle col^=(col>>2)&7 (bijective, 16B-granular): b128
//    writes conflict-free (was 32-way at 64B lane stride), reads stay free.
// Unchanged from r12: 21KB LDS, all-b128 fragments, lgkm-only barriers,
// grid 1024 (node=bid&255 -> same-XCD W dedupe), fp16 MFMA layouts (r3-r12),
// gemm2 slab bounces, phase2.

#define BN 256
#define HD 256
#define FD 64
#define NHD (BN * HD)
#define XS 40    // X/slab row stride (halves)

typedef _Float16 f16x8 __attribute__((ext_vector_type(8)));
typedef _Float16 f16x4 __attribute__((ext_vector_type(4)));
typedef float f32x4 __attribute__((ext_vector_type(4)));

#define BAR_LGKM()                                                         \
  asm volatile("s_waitcnt lgkmcnt(0)" ::: "memory");                       \
  __builtin_amdgcn_s_barrier();                                            \
  asm volatile("" ::: "memory");

__device__ __forceinline__ int wswz(int col) { return col ^ ((col >> 2) & 7); }

// ---------- X staging: 64 rows x 32 k fp32 -> regs -> fp16 LDS ----------
__device__ __forceinline__ void x_load(const float* xs0, const float* xs1, int n,
                                       int row0, int kt, int tid, float4 xr[2]) {
  int kOff = kt * 32;
  const float* xs = (kOff < 256) ? xs0 : xs1;   // A-branch: obs then act
  int row = tid >> 2, c = (tid & 3) * 4;
  const float* p = xs + (size_t)(row0 + row) * NHD + n * HD + (kOff & 255) + c;
  xr[0] = *(const float4*)p;
  xr[1] = *(const float4*)(p + 16);
}
__device__ __forceinline__ void x_write(_Float16* Xl, int tid, const float4 xr[2]) {
  int row = tid >> 2, c = (tid & 3) * 4;
  f16x4 a, b;
  a[0] = (_Float16)xr[0].x; a[1] = (_Float16)xr[0].y;
  a[2] = (_Float16)xr[0].z; a[3] = (_Float16)xr[0].w;
  b[0] = (_Float16)xr[1].x; b[1] = (_Float16)xr[1].y;
  b[2] = (_Float16)xr[1].z; b[3] = (_Float16)xr[1].w;
  *(f16x4*)(Xl + row * XS + c) = a;
  *(f16x4*)(Xl + row * XS + c + 16) = b;
}

// ---------- W1 stage, split: issue 8x float4 -> commit cvt + 4x b128 ----------
// Wave w owns k-rows w*8..w*8+7 (khi = w). Lane l owns cols 4l..4l+3.
__device__ __forceinline__ void w1_issue(const float* __restrict__ Wg, int kt,
                                         int w, int l, float4 wr[8]) {
  const float* p = Wg + (size_t)(kt * 32 + w * 8) * HD + 4 * l;
#pragma unroll
  for (int r = 0; r < 8; ++r) wr[r] = *(const float4*)(p + (size_t)r * HD);
}
__device__ __forceinline__ void w1_commit(_Float16* Wl, int w, int l,
                                          const float4 wr[8]) {
  // j static in unrolled loop (rule #20: no runtime component indexing)
#pragma unroll
  for (int j = 0; j < 4; ++j) {
    f16x8 v;
    v[0] = (_Float16)((j == 0) ? wr[0].x : (j == 1) ? wr[0].y : (j == 2) ? wr[0].z : wr[0].w);
    v[1] = (_Float16)((j == 0) ? wr[1].x : (j == 1) ? wr[1].y : (j == 2) ? wr[1].z : wr[1].w);
    v[2] = (_Float16)((j == 0) ? wr[2].x : (j == 1) ? wr[2].y : (j == 2) ? wr[2].z : wr[2].w);
    v[3] = (_Float16)((j == 0) ? wr[3].x : (j == 1) ? wr[3].y : (j == 2) ? wr[3].z : wr[3].w);
    v[4] = (_Float16)((j == 0) ? wr[4].x : (j == 1) ? wr[4].y : (j == 2) ? wr[4].z : wr[4].w);
    v[5] = (_Float16)((j == 0) ? wr[5].x : (j == 1) ? wr[5].y : (j == 2) ? wr[5].z : wr[5].w);
    v[6] = (_Float16)((j == 0) ? wr[6].x : (j == 1) ? wr[6].y : (j == 2) ? wr[6].z : wr[6].w);
    v[7] = (_Float16)((j == 0) ? wr[7].x : (j == 1) ? wr[7].y : (j == 2) ? wr[7].z : wr[7].w);
    *(f16x8*)(Wl + (size_t)(w * 256 + wswz(4 * l + j)) * 8) = v;  // conflict-free
  }
}

// ---------- W2 half stage (JIT, r12 pattern): [khi=16][64 col][klo=8] ----------
__device__ __forceinline__ void w2_stage(const float* __restrict__ W2g, _Float16* Wl,
                                         int half, int w, int l) {
#pragma unroll
  for (int cg = 0; cg < 4; ++cg) {
    int khi = w * 4 + cg;
    const float* p = W2g + (size_t)(half * 128 + khi * 8) * FD + l;
    f16x8 v;
#pragma unroll
    for (int r = 0; r < 8; ++r) v[r] = (_Float16)p[(size_t)r * FD];
    *(f16x8*)(Wl + ((size_t)(khi * 64 + l)) * 8) = v;
  }
}

// ---------- GEMM1 compute: one 32-k step, 16 MFMA/wave, all-b128 frags ----------
__device__ __forceinline__ void g1_compute(const _Float16* Wl, const _Float16* Xl,
                                           int lrow, int lq, const int wcol[4],
                                           f32x4 acc[4][4]) {
  f16x8 b[4];
#pragma unroll
  for (int nf = 0; nf < 4; ++nf)
    b[nf] = *(const f16x8*)(Wl + (size_t)(lq * 256 + wcol[nf]) * 8);
#pragma unroll
  for (int m = 0; m < 4; ++m) {
    f16x8 a = *(const f16x8*)(Xl + (m * 16 + lrow) * XS + lq * 8);
#pragma unroll
    for (int nf = 0; nf < 4; ++nf)
      acc[m][nf] = __builtin_amdgcn_mfma_f32_16x16x32_f16(a, b[nf], acc[m][nf], 0, 0, 0);
  }
}

// C1(64x256) = X(64xK) @ W1(Kx256), K = NK*32.
template <int NK>
__device__ __forceinline__ void run_gemm1(const float* xs0, const float* xs1,
                                          const float* __restrict__ Wg,
                                          int n, int row0, int tid, int lrow, int lq,
                                          const int wcol[4], int w, int l,
                                          _Float16* Wl, _Float16* Xl,
                                          f32x4 acc[4][4]) {
  float4 wr[8];
  float4 xr[2];
  w1_issue(Wg, 0, w, l, wr);
  x_load(xs0, xs1, n, row0, 0, tid, xr);
  w1_commit(Wl, w, l, wr);                 // prologue: latency exposed once
  x_write(Xl, tid, xr);
#pragma unroll 1
  for (int kt = 0; kt < NK; ++kt) {
    BAR_LGKM();                            // tile kt published
    if (kt + 1 < NK) {                     // issue-early: in flight under compute
      w1_issue(Wg, kt + 1, w, l, wr);
      x_load(xs0, xs1, n, row0, kt + 1, tid, xr);
    }
    g1_compute(Wl, Xl, lrow, lq, wcol, acc);
    BAR_LGKM();                            // all reads of tile kt done
    if (kt + 1 < NK) {
      w1_commit(Wl, w, l, wr);             // commit-late (waits its own batch)
      x_write(Xl, tid, xr);
    }
  }
}

// ---------- GEMM2: C2(64x64) += relu(C1+b1) @ W2, 8 x 32-k slab bounces ----------
__device__ __forceinline__ void gemm2_branch(const f32x4 acc[4][4], f32x4 acc2[4],
                                             const float* __restrict__ W2g,
                                             const float* __restrict__ b1g,
                                             _Float16* Wl, _Float16* slab,
                                             int lrow, int lq, int Nbase, int w, int l) {
  float bv[4];
#pragma unroll
  for (int nf = 0; nf < 4; ++nf) bv[nf] = b1g[Nbase + nf * 16 + lrow];  // L2-hot
  w2_stage(W2g, Wl, 0, w, l);              // W1 reads done (caller's last barrier)
#pragma unroll
  for (int s = 0; s < 8; ++s) {
    if (w == (s >> 1)) {
#pragma unroll
      for (int m = 0; m < 4; ++m)
#pragma unroll
        for (int nf2 = 0; nf2 < 2; ++nf2) {
          const int nf = (s & 1) * 2 + nf2;  // static
#pragma unroll
          for (int r = 0; r < 4; ++r)
            slab[(m * 16 + lq * 4 + r) * XS + nf2 * 16 + lrow] =
                (_Float16)fmaxf(acc[m][nf][r] + bv[nf], 0.f);
        }
    }
    BAR_LGKM();                            // slab (+W2-half writes) published
    f16x8 a2 = *(const f16x8*)(slab + (w * 16 + lrow) * XS + lq * 8);
    f16x8 bb[4];
#pragma unroll
    for (int nf = 0; nf < 4; ++nf)
      bb[nf] = *(const f16x8*)(Wl + ((size_t)(((s & 3) * 4 + lq) * 64 + nf * 16 + lrow)) * 8);
#pragma unroll
    for (int nf = 0; nf < 4; ++nf)
      acc2[nf] = __builtin_amdgcn_mfma_f32_16x16x32_f16(a2, bb[nf], acc2[nf], 0, 0, 0);
    BAR_LGKM();                            // reads done before next writer/stage
    if (s == 3) w2_stage(W2g, Wl, 1, w, l);
  }
}

__global__ __launch_bounds__(256, 3) void phase1_kernel(
    const float* __restrict__ obs, const float* __restrict__ act,
    const float* __restrict__ V_W1, const float* __restrict__ V_b1,
    const float* __restrict__ V_W2, const float* __restrict__ V_b2,
    const float* __restrict__ A_W1, const float* __restrict__ A_b1,
    const float* __restrict__ A_W2, const float* __restrict__ A_b2,
    float* __restrict__ Q) {
  __shared__ __align__(16) _Float16 Wl[8192];   // 16KB: W1 [4][256swz][8] / W2 [16][64][8]
  __shared__ __align__(16) _Float16 Xl[2560];   // 5KB: X [64][40] / h slab

  int tid = threadIdx.x;
  int l = tid & 63, w = tid >> 6;
  int lrow = l & 15, lq = l >> 4;
  int Nbase = w * 64;
  int wcol[4];
#pragma unroll
  for (int nf = 0; nf < 4; ++nf) wcol[nf] = wswz(Nbase + nf * 16 + lrow);
  int bid = blockIdx.x;
  int n = bid & 255;                   // node; 4 quarters share an XCD
  int row0 = (bid >> 8) * 64;          // batch quarter

  f32x4 acc[4][4];
  f32x4 acc2[4];
#pragma unroll
  for (int j = 0; j < 4; ++j) acc2[j] = (f32x4){0.f, 0.f, 0.f, 0.f};

  // ---------------- V branch (NK=8) ----------------
#pragma unroll
  for (int m = 0; m < 4; ++m)
#pragma unroll
    for (int nf = 0; nf < 4; ++nf) acc[m][nf] = (f32x4){0.f, 0.f, 0.f, 0.f};
  run_gemm1<8>(obs, obs, V_W1 + (size_t)n * HD * HD, n, row0, tid, lrow, lq,
               wcol, w, l, Wl, Xl, acc);
  gemm2_branch(acc, acc2, V_W2 + (size_t)n * HD * FD, V_b1 + n * HD,
               Wl, Xl, lrow, lq, Nbase, w, l);

  // ---------------- A branch (NK=16) ----------------
#pragma unroll
  for (int m = 0; m < 4; ++m)
#pragma unroll
    for (int nf = 0; nf < 4; ++nf) acc[m][nf] = (f32x4){0.f, 0.f, 0.f, 0.f};
  run_gemm1<16>(obs, act, A_W1 + (size_t)n * 2 * HD * HD, n, row0, tid, lrow, lq,
                wcol, w, l, Wl, Xl, acc);
  gemm2_branch(acc, acc2, A_W2 + (size_t)n * HD * FD, A_b1 + n * HD,
               Wl, Xl, lrow, lq, Nbase, w, l);

  // ---------------- Q = acc2 + V_b2 + A_b2 ----------------
  const float* vb2 = V_b2 + n * FD;
  const float* ab2 = A_b2 + n * FD;
#pragma unroll
  for (int nf = 0; nf < 4; ++nf) {
    int f = nf * 16 + lrow;
    float bias = vb2[f] + ab2[f];
#pragma unroll
    for (int rr = 0; rr < 4; ++rr) {
      int row = row0 + w * 16 + lq * 4 + rr;
      Q[(size_t)row * (BN * FD) + n * FD + f] = acc2[nf][rr] + bias;
    }
  }
}

// ---------------- phase 2: gather + subset-min + chi + mean ----------------
__global__ __launch_bounds__(256) void phase2_kernel(const float* __restrict__ Q,
                                                     const float* __restrict__ chi_m,
                                                     const int* __restrict__ le,
                                                     float* __restrict__ out) {
  int b = blockIdx.x;
  int n = threadIdx.x;
  // int64-vs-int32 layout hedge: centers = arange(N) => int32 layout has le[5]==1.
  int step = (le[5] == 1) ? 1 : 2;
  const int* e = le + n * 5 * step;
  int c  = e[0 * step] & (BN - 1);
  int n0 = e[1 * step] & (BN - 1);
  int n1 = e[2 * step] & (BN - 1);
  int n2 = e[3 * step] & (BN - 1);
  int n3 = e[4 * step] & (BN - 1);
  const float* ch = chi_m + n * 45;   // (HEADS=3, S=15)
  float cm[15];
#pragma unroll
  for (int s = 0; s < 15; ++s) cm[s] = (ch[s] + ch[15 + s] + ch[30 + s]) * (1.f / 3.f);
  const float* qb = Q + (size_t)b * (BN * FD);
  const float* q0 = qb + n0 * FD;
  const float* q1 = qb + n1 * FD;
  const float* q2 = qb + n2 * FD;
  const float* q3 = qb + n3 * FD;
  const float* qc = qb + c * FD;
  float acc = 0.f;
#pragma unroll
  for (int f = 0; f < FD; f += 4) {
    float4 v0 = *(const float4*)(q0 + f);
    float4 v1 = *(const float4*)(q1 + f);
    float4 v2 = *(const float4*)(q2 + f);
    float4 v3 = *(const float4*)(q3 + f);
    float4 vc = *(const float4*)(qc + f);
    const float* p0 = (const float*)&v0;
    const float* p1 = (const float*)&v1;
    const float* p2 = (const float*)&v2;
    const float* p3 = (const float*)&v3;
    const float* pc = (const float*)&vc;
#pragma unroll
    for (int u = 0; u < 4; ++u) {
      float a = p0[u], bq = p1[u], cq = p2[u], d = p3[u];
      float m01 = fminf(a, bq), m02 = fminf(a, cq), m03 = fminf(a, d);
      float m12 = fminf(bq, cq), m13 = fminf(bq, d), m23 = fminf(cq, d);
      float m012 = fminf(m01, cq), m013 = fminf(m01, d);
      float m023 = fminf(m02, d),  m123 = fminf(m12, d);
      float m0123 = fminf(m01, m23);
      float chi = cm[0] * a   + cm[1] * bq   + cm[2] * m01  + cm[3] * cq
                + cm[4] * m02 + cm[5] * m12  + cm[6] * m012 + cm[7] * d
                + cm[8] * m03 + cm[9] * m13  + cm[10] * m013 + cm[11] * m23
                + cm[12] * m023 + cm[13] * m123 + cm[14] * m0123;
      acc += chi + pc[u];
    }
  }
  out[b * BN + n] = acc * (1.f / 64.f);
}

extern "C" void kernel_launch(void* const* d_in, const int* in_sizes, int n_in,
                              void* d_out, int out_size, void* d_ws, size_t ws_size,
                              hipStream_t stream) {
  (void)in_sizes; (void)n_in; (void)out_size; (void)ws_size;
  const float* obs  = (const float*)d_in[0];
  const float* act  = (const float*)d_in[1];
  const float* V_W1 = (const float*)d_in[2];
  const float* V_b1 = (const float*)d_in[3];
  const float* V_W2 = (const float*)d_in[4];
  const float* V_b2 = (const float*)d_in[5];
  const float* A_W1 = (const float*)d_in[6];
  const float* A_b1 = (const float*)d_in[7];
  const float* A_W2 = (const float*)d_in[8];
  const float* A_b2 = (const float*)d_in[9];
  const float* chim = (const float*)d_in[10];
  const int*   le   = (const int*)d_in[11];
  float* Q   = (float*)d_ws;            // 16 MB scratch: Q[B][N][F]
  float* out = (float*)d_out;

  phase1_kernel<<<dim3(1024), dim3(256), 0, stream>>>(obs, act, V_W1, V_b1, V_W2, V_b2,
                                                      A_W1, A_b1, A_W2, A_b2, Q);
  phase2_kernel<<<dim3(256), dim3(256), 0, stream>>>(Q, chim, le, out);
}